// Round 2
// baseline (4234.789 us; speedup 1.0000x reference)
//
#include <hip/hip_runtime.h>
#include <hip/hip_bf16.h>

#define NCRYST 256
#define AATOMS 64
#define KNBR   20
#define HID    128
#define LAT    256
#define NRBF   128
#define NBLK   3
#define NATOMS (NCRYST * AATOMS)   // 16384
#define NEDGE  (NATOMS * KNBR)     // 327680
#define PI_F   3.14159265358979323846f
#define CUT_F  6.0f

__device__ __forceinline__ float bf2f(__hip_bfloat16 x) { return __bfloat162float(x); }
__device__ __forceinline__ __hip_bfloat16 f2bf(float x) { return __float2bfloat16(x); }

// rbf_j(d) = exp(-((d - mu_j)/delta)^2) * env(d),  mu_j = j*6/127, delta = 6/127
__device__ __forceinline__ float rbf_val(float d, int j) {
  float env = 0.5f * (cosf(PI_F * fminf(d * (1.f/CUT_F), 1.f)) + 1.f);
  float t = (d - (float)j * (CUT_F/(NRBF-1))) * ((NRBF-1)/CUT_F);
  return expf(-t*t) * env;
}

// ---------------------------------------------------------------- cart coords
__global__ void k_cart(const float* __restrict__ frac, const float* __restrict__ lengths,
                       const float* __restrict__ angles, float* __restrict__ cart) {
  int atom = blockIdx.x * blockDim.x + threadIdx.x;
  if (atom >= NATOMS) return;
  int c = atom >> 6;
  float al = angles[c*3+0] * (PI_F/180.f);
  float be = angles[c*3+1] * (PI_F/180.f);
  float ga = angles[c*3+2] * (PI_F/180.f);
  float ca = cosf(al), cb = cosf(be), cg = cosf(ga), sg = sinf(ga);
  float a = lengths[c*3+0], b = lengths[c*3+1], cl = lengths[c*3+2];
  float cx = cl * cb;
  float cy = cl * (ca - cb*cg) / sg;
  float cz = sqrtf(fmaxf(cl*cl - cx*cx - cy*cy, 1e-8f));
  float f0 = frac[atom*3+0], f1 = frac[atom*3+1], f2 = frac[atom*3+2];
  cart[atom*3+0] = f0*a + f1*(b*cg) + f2*cx;
  cart[atom*3+1] = f1*(b*sg) + f2*cy;
  cart[atom*3+2] = f2*cz;
}

// ------------------------------------------- edge geometry: dist + unit only
__global__ void k_edge(const float* __restrict__ cart, const int* __restrict__ src,
                       const int* __restrict__ dst, float* __restrict__ unit,
                       float* __restrict__ dist) {
  int e = blockIdx.x * blockDim.x + threadIdx.x;
  if (e >= NEDGE) return;
  int s = src[e], d = dst[e];
  float dx = cart[d*3+0] - cart[s*3+0];
  float dy = cart[d*3+1] - cart[s*3+1];
  float dz = cart[d*3+2] - cart[s*3+2];
  float dd = sqrtf(dx*dx + dy*dy + dz*dz + 1e-12f);
  float inv = 1.f / dd;
  dist[e] = dd;
  unit[e*3+0] = dx*inv; unit[e*3+1] = dy*inv; unit[e*3+2] = dz*inv;
}

// --------------------------------------------------- 8-row block GEMM helper
// 128 threads; thread `tid` owns output column `tid` for 8 rows.
template<int KD>
__device__ __forceinline__ void gemm8(const float* __restrict__ W,
                                      const float (*in)[KD], float acc[8], int tid) {
#pragma unroll 2
  for (int k4 = 0; k4 < KD/4; ++k4) {
    float w0 = W[(k4*4+0)*HID + tid];
    float w1 = W[(k4*4+1)*HID + tid];
    float w2 = W[(k4*4+2)*HID + tid];
    float w3 = W[(k4*4+3)*HID + tid];
#pragma unroll
    for (int r = 0; r < 8; ++r) {
      const float4 v = *reinterpret_cast<const float4*>(&in[r][k4*4]);
      acc[r] = fmaf(v.x, w0, acc[r]);
      acc[r] = fmaf(v.y, w1, acc[r]);
      acc[r] = fmaf(v.z, w2, acc[r]);
      acc[r] = fmaf(v.w, w3, acc[r]);
    }
  }
}

// --------------------------------------------------------- h = relu([emb|z]W)
__global__ void k_h(const int* __restrict__ atype, const float* __restrict__ z,
                    const float* __restrict__ emb, const float* __restrict__ W,
                    const float* __restrict__ b, float* __restrict__ h) {
  __shared__ __align__(16) float in[8][384];
  int tid = threadIdx.x;
  int row0 = blockIdx.x * 8;
#pragma unroll
  for (int r = 0; r < 8; ++r) {
    int atom = row0 + r;
    in[r][tid]     = emb[atype[atom]*HID + tid];
    int cb = (atom >> 6) * LAT;
    in[r][tid+128] = z[cb + tid];
    in[r][tid+256] = z[cb + 128 + tid];
  }
  __syncthreads();
  float acc[8] = {0,0,0,0,0,0,0,0};
  gemm8<384>(W, in, acc, tid);
  float bias = b[tid];
#pragma unroll
  for (int r = 0; r < 8; ++r)
    h[(row0+r)*HID + tid] = fmaxf(acc[r] + bias, 0.f);
}

// ----------------- edge GEMM: [h[src]|h[dst]|third] @ W  (K = 384), bf16 out
// mode 0: third = rbf(dist)   out = bf16(relu(acc+b))
// mode 1: third = m (bf16)    out = bf16(m + relu(acc+b))  (in-place m update)
__global__ void k_edge_gemm(const int* __restrict__ src, const int* __restrict__ dst,
                            const float* __restrict__ h,
                            const __hip_bfloat16* __restrict__ m_in,
                            const float* __restrict__ distA,
                            const float* __restrict__ W, const float* __restrict__ b,
                            __hip_bfloat16* __restrict__ out, int mode) {
  __shared__ __align__(16) float in[8][384];
  __shared__ int sidx[8], didx[8];
  __shared__ float sdist[8];
  int tid = threadIdx.x;
  int row0 = blockIdx.x * 8;
  if (tid < 8)       sidx[tid]     = src[row0 + tid];
  else if (tid < 16) didx[tid-8]   = dst[row0 + tid - 8];
  else if (tid < 24) sdist[tid-16] = distA[row0 + tid - 16];
  __syncthreads();
#pragma unroll
  for (int r = 0; r < 8; ++r) {
    in[r][tid]     = h[sidx[r]*HID + tid];
    in[r][tid+128] = h[didx[r]*HID + tid];
    in[r][tid+256] = (mode == 0) ? rbf_val(sdist[r], tid)
                                 : bf2f(m_in[(row0+r)*HID + tid]);
  }
  __syncthreads();
  float acc[8] = {0,0,0,0,0,0,0,0};
  gemm8<384>(W, in, acc, tid);
  float bias = b[tid];
#pragma unroll
  for (int r = 0; r < 8; ++r) {
    float v = fmaxf(acc[r] + bias, 0.f);
    if (mode) v += in[r][256 + tid];
    out[(row0+r)*HID + tid] = f2bf(v);
  }
}

// ---------- msg = relu(m@Wm + bm) * (rbf@Wg), rbf recomputed, bf16 in/out
__global__ void k_msg(const __hip_bfloat16* __restrict__ m,
                      const float* __restrict__ distA,
                      const float* __restrict__ Wm, const float* __restrict__ bm,
                      const float* __restrict__ Wg,
                      __hip_bfloat16* __restrict__ msg) {
  __shared__ __align__(16) float im[8][128];
  __shared__ __align__(16) float ig[8][128];
  __shared__ float sdist[8];
  int tid = threadIdx.x;
  int row0 = blockIdx.x * 8;
  if (tid < 8) sdist[tid] = distA[row0 + tid];
  __syncthreads();
#pragma unroll
  for (int r = 0; r < 8; ++r) {
    im[r][tid] = bf2f(m[(row0+r)*HID + tid]);
    ig[r][tid] = rbf_val(sdist[r], tid);
  }
  __syncthreads();
  float accM[8] = {0,0,0,0,0,0,0,0};
  float accG[8] = {0,0,0,0,0,0,0,0};
  gemm8<128>(Wm, im, accM, tid);
  gemm8<128>(Wg, ig, accG, tid);
  float bias = bm[tid];
#pragma unroll
  for (int r = 0; r < 8; ++r)
    msg[(row0+r)*HID + tid] = f2bf(fmaxf(accM[r] + bias, 0.f) * accG[r]);
}

// ------------------------------------- per-crystal segment sum (no atomics)
__global__ void k_segsum(const __hip_bfloat16* __restrict__ msg,
                         const int* __restrict__ dst, float* __restrict__ agg) {
  __shared__ float acc[AATOMS * HID];   // 32 KB
  __shared__ int   sdst[1280];
  int c = blockIdx.x, j = threadIdx.x;  // 128 threads: thread j owns column j
  for (int i = j; i < AATOMS*HID; i += 128) acc[i] = 0.f;
  int ebase = c * 1280;
  for (int i = j; i < 1280; i += 128) sdst[i] = dst[ebase + i] & 63;
  __syncthreads();
  for (int t = 0; t < 1280; ++t) {
    int d = sdst[t];
    acc[d*HID + j] += bf2f(msg[(ebase + t)*HID + j]);
  }
  __syncthreads();
  for (int a = 0; a < AATOMS; ++a)
    agg[(c*AATOMS + a)*HID + j] = acc[a*HID + j];
}

// -------------------------- dense-row K=128 GEMM: Y = relu(X@W+b) [+= mode 1]
__global__ void k_fc(const float* __restrict__ X, const float* __restrict__ W,
                     const float* __restrict__ b, float* __restrict__ Y, int mode) {
  __shared__ __align__(16) float ix[8][128];
  int tid = threadIdx.x;
  int row0 = blockIdx.x * 8;
#pragma unroll
  for (int r = 0; r < 8; ++r) ix[r][tid] = X[(row0+r)*HID + tid];
  __syncthreads();
  float acc[8] = {0,0,0,0,0,0,0,0};
  gemm8<128>(W, ix, acc, tid);
  float bias = b[tid];
#pragma unroll
  for (int r = 0; r < 8; ++r) {
    float v = fmaxf(acc[r] + bias, 0.f);
    int o = (row0+r)*HID + tid;
    if (mode) v += Y[o];
    Y[o] = v;
  }
}

// ------------------------------------------------- f = m @ W_force + b_force
__global__ void k_force(const __hip_bfloat16* __restrict__ m,
                        const float* __restrict__ Wf,
                        const float* __restrict__ bf, float* __restrict__ f) {
  int lane = threadIdx.x & 63;
  int wave = threadIdx.x >> 6;
  int ebase = blockIdx.x * 64 + wave * 16;
  float w0 = Wf[lane], w1 = Wf[64 + lane];
  float b = bf[0];
  for (int t = 0; t < 16; ++t) {
    int e = ebase + t;
    float p = bf2f(m[e*HID + lane]) * w0 + bf2f(m[e*HID + 64 + lane]) * w1;
#pragma unroll
    for (int off = 32; off > 0; off >>= 1) p += __shfl_down(p, off, 64);
    if (lane == 0) f[e] = p + b;
  }
}

// ----------------------------------- pred_cart = segsum(f*unit) per crystal
__global__ void k_pcart(const float* __restrict__ f, const float* __restrict__ unit,
                        const int* __restrict__ dst, float* __restrict__ out) {
  __shared__ float acc[AATOMS * 3];
  int c = blockIdx.x, tid = threadIdx.x;  // 256 threads
  if (tid < AATOMS*3) acc[tid] = 0.f;
  __syncthreads();
  for (int t = tid; t < 1280; t += 256) {
    int e = c*1280 + t;
    int d = dst[e] & 63;
    float fv = f[e];
    atomicAdd(&acc[d*3+0], fv * unit[e*3+0]);
    atomicAdd(&acc[d*3+1], fv * unit[e*3+1]);
    atomicAdd(&acc[d*3+2], fv * unit[e*3+2]);
  }
  __syncthreads();
  if (tid < AATOMS*3) out[c*AATOMS*3 + tid] = acc[tid];
}

// ----------------------------------------- final fc3: (128 -> 2) per atom row
__global__ void k_fc3(const float* __restrict__ a2, const float* __restrict__ W,
                      const float* __restrict__ b, float* __restrict__ out) {
  int lane = threadIdx.x & 63;
  int wave = threadIdx.x >> 6;
  int row = blockIdx.x * 4 + wave;
  float x0 = a2[row*HID + lane], x1 = a2[row*HID + 64 + lane];
  float p0 = x0 * W[lane*2+0] + x1 * W[(64+lane)*2+0];
  float p1 = x0 * W[lane*2+1] + x1 * W[(64+lane)*2+1];
#pragma unroll
  for (int off = 32; off > 0; off >>= 1) {
    p0 += __shfl_down(p0, off, 64);
    p1 += __shfl_down(p1, off, 64);
  }
  if (lane == 0) {
    out[row*2+0] = p0 + b[0];
    out[row*2+1] = p1 + b[1];
  }
}

extern "C" void kernel_launch(void* const* d_in, const int* in_sizes, int n_in,
                              void* d_out, int out_size, void* d_ws, size_t ws_size,
                              hipStream_t stream) {
  const float* z        = (const float*)d_in[0];
  const float* frac     = (const float*)d_in[1];
  const float* lengths  = (const float*)d_in[2];
  const float* angles   = (const float*)d_in[3];
  const int*   atype    = (const int*)  d_in[4];
  const int*   src      = (const int*)  d_in[5];
  const int*   dst      = (const int*)  d_in[6];
  const float* emb      = (const float*)d_in[7];
  const float* W_in     = (const float*)d_in[8];
  const float* b_in     = (const float*)d_in[9];
  const float* W_edge   = (const float*)d_in[10];
  const float* b_edge   = (const float*)d_in[11];
  const float* Wb_rbf   = (const float*)d_in[12];
  const float* Wb_msg   = (const float*)d_in[13];
  const float* bb_msg   = (const float*)d_in[14];
  const float* Wb_atom  = (const float*)d_in[15];
  const float* bb_atom  = (const float*)d_in[16];
  const float* Wb_upd   = (const float*)d_in[17];
  const float* bb_upd   = (const float*)d_in[18];
  const float* W_force  = (const float*)d_in[19];
  const float* b_force  = (const float*)d_in[20];
  const float* W_fc1    = (const float*)d_in[21];
  const float* b_fc1    = (const float*)d_in[22];
  const float* W_fc2    = (const float*)d_in[23];
  const float* b_fc2    = (const float*)d_in[24];
  const float* W_fc3    = (const float*)d_in[25];
  const float* b_fc3    = (const float*)d_in[26];

  // ---- workspace layout (~190 MB total; all region starts 16B-aligned) ----
  char* p = (char*)d_ws;
  float* cart = (float*)p;            p += (size_t)NATOMS*3*4;      //  0.2 MB
  float* unit = (float*)p;            p += (size_t)NEDGE*3*4;       //  3.9 MB
  float* dist = (float*)p;            p += (size_t)NEDGE*4;         //  1.3 MB
  float* h    = (float*)p;            p += (size_t)NATOMS*HID*4;    //  8.4 MB
  float* agg  = (float*)p;            p += (size_t)NATOMS*HID*4;    //  8.4 MB
  __hip_bfloat16* m   = (__hip_bfloat16*)p; p += (size_t)NEDGE*HID*2;  // 83.9 MB
  __hip_bfloat16* msg = (__hip_bfloat16*)p; p += (size_t)NEDGE*HID*2;  // 83.9 MB
  // msg region is dead after the last segsum -> overlay f / a1 / a2 there
  float* f  = (float*)msg;                 // NEDGE f32 (1.3 MB)
  float* a1 = f + NEDGE;                   // NATOMS*HID f32
  float* a2 = a1 + NATOMS*HID;             // NATOMS*HID f32 (total 18 MB < 84 MB)

  float* out_cart = (float*)d_out;         // 16384*3
  float* out_at   = out_cart + NATOMS*3;   // 16384*2

  k_cart<<<NATOMS/256, 256, 0, stream>>>(frac, lengths, angles, cart);
  k_edge<<<NEDGE/256, 256, 0, stream>>>(cart, src, dst, unit, dist);
  k_h<<<NATOMS/8, 128, 0, stream>>>(atype, z, emb, W_in, b_in, h);
  k_edge_gemm<<<NEDGE/8, 128, 0, stream>>>(src, dst, h, m, dist, W_edge, b_edge, m, 0);

  for (int i = 0; i < NBLK; ++i) {
    k_msg<<<NEDGE/8, 128, 0, stream>>>(m, dist, Wb_msg + i*HID*HID, bb_msg + i*HID,
                                       Wb_rbf + i*NRBF*HID, msg);
    k_segsum<<<NCRYST, 128, 0, stream>>>(msg, dst, agg);
    k_fc<<<NATOMS/8, 128, 0, stream>>>(agg, Wb_atom + i*HID*HID, bb_atom + i*HID, h, 1);
    k_edge_gemm<<<NEDGE/8, 128, 0, stream>>>(src, dst, h, m, dist,
                                             Wb_upd + i*3*HID*HID, bb_upd + i*HID, m, 1);
  }

  k_force<<<NEDGE/64, 256, 0, stream>>>(m, W_force, b_force, f);
  k_pcart<<<NCRYST, 256, 0, stream>>>(f, unit, dst, out_cart);
  k_fc<<<NATOMS/8, 128, 0, stream>>>(h, W_fc1, b_fc1, a1, 0);
  k_fc<<<NATOMS/8, 128, 0, stream>>>(a1, W_fc2, b_fc2, a2, 0);
  k_fc3<<<NATOMS/4, 256, 0, stream>>>(a2, W_fc3, b_fc3, out_at);
}

// Round 3
// 2292.097 us; speedup vs baseline: 1.8476x; 1.8476x over previous
//
#include <hip/hip_runtime.h>
#include <hip/hip_bf16.h>

#define NCRYST 256
#define AATOMS 64
#define KNBR   20
#define HID    128
#define LAT    256
#define NRBF   128
#define NBLK   3
#define NATOMS (NCRYST * AATOMS)   // 16384
#define NEDGE  (NATOMS * KNBR)     // 327680
#define PI_F   3.14159265358979323846f
#define CUT_F  6.0f

typedef short short8 __attribute__((ext_vector_type(8)));   // 8 bf16 (4 VGPRs)
typedef float f32x4  __attribute__((ext_vector_type(4)));   // MFMA C/D

__device__ __forceinline__ float bf2f(__hip_bfloat16 x) { return __bfloat162float(x); }
__device__ __forceinline__ __hip_bfloat16 f2bf(float x) { return __float2bfloat16(x); }

// ---------------------------------------------------------------- cart coords
__global__ void k_cart(const float* __restrict__ frac, const float* __restrict__ lengths,
                       const float* __restrict__ angles, float* __restrict__ cart) {
  int atom = blockIdx.x * blockDim.x + threadIdx.x;
  if (atom >= NATOMS) return;
  int c = atom >> 6;
  float al = angles[c*3+0] * (PI_F/180.f);
  float be = angles[c*3+1] * (PI_F/180.f);
  float ga = angles[c*3+2] * (PI_F/180.f);
  float ca = cosf(al), cb = cosf(be), cg = cosf(ga), sg = sinf(ga);
  float a = lengths[c*3+0], b = lengths[c*3+1], cl = lengths[c*3+2];
  float cx = cl * cb;
  float cy = cl * (ca - cb*cg) / sg;
  float cz = sqrtf(fmaxf(cl*cl - cx*cx - cy*cy, 1e-8f));
  float f0 = frac[atom*3+0], f1 = frac[atom*3+1], f2 = frac[atom*3+2];
  cart[atom*3+0] = f0*a + f1*(b*cg) + f2*cx;
  cart[atom*3+1] = f1*(b*sg) + f2*cy;
  cart[atom*3+2] = f2*cz;
}

// ---------------- edge geometry: unit vec + rbf (bf16, computed ONCE)
// 256 threads = 2 edges x 128 rbf columns
__global__ void k_edge(const float* __restrict__ cart, const int* __restrict__ src,
                       const int* __restrict__ dst, float* __restrict__ unit,
                       __hip_bfloat16* __restrict__ rbf) {
  int e = blockIdx.x * 2 + (threadIdx.x >> 7);
  int j = threadIdx.x & 127;
  int s = src[e], d = dst[e];
  float dx = cart[d*3+0] - cart[s*3+0];
  float dy = cart[d*3+1] - cart[s*3+1];
  float dz = cart[d*3+2] - cart[s*3+2];
  float dd = sqrtf(dx*dx + dy*dy + dz*dz + 1e-12f);
  float inv = 1.f / dd;
  if (j == 0) {
    unit[e*3+0] = dx*inv; unit[e*3+1] = dy*inv; unit[e*3+2] = dz*inv;
  }
  float env = 0.5f * (cosf(PI_F * fminf(dd * (1.f/CUT_F), 1.f)) + 1.f);
  float t = (dd - (float)j * (CUT_F/(NRBF-1))) * ((NRBF-1)/CUT_F);
  rbf[e*NRBF + j] = f2bf(expf(-t*t) * env);
}

// ----------------- weights: transpose + cast to bf16, W_T[n][k] = W[k][n]
// big: W_edge, Wb_upd[0..2]  (384x128 -> 128x384), 4*49152 elems
// small: Wb_msg[0..2], Wb_rbf[0..2] (128x128 -> 128x128), 6*16384 elems
__global__ void k_wcast(const float* __restrict__ W_edge, const float* __restrict__ Wb_upd,
                        const float* __restrict__ Wb_msg, const float* __restrict__ Wb_rbf,
                        __hip_bfloat16* __restrict__ WT) {
  int idx = blockIdx.x * 256 + threadIdx.x;
  if (idx < 196608) {
    int j = idx / 49152, t = idx % 49152;
    int n = t / 384, k = t % 384;
    const float* srcW = (j == 0) ? W_edge : (Wb_upd + (j-1)*49152);
    WT[idx] = f2bf(srcW[k*128 + n]);
  } else {
    int t = idx - 196608;
    int j = t / 16384, q = t % 16384;
    int n = q / 128, k = q % 128;
    const float* srcW = (j < 3) ? (Wb_msg + j*16384) : (Wb_rbf + (j-3)*16384);
    WT[idx] = f2bf(srcW[k*128 + n]);
  }
}

// --------------------------------------------------- 8-row block GEMM helper
template<int KD>
__device__ __forceinline__ void gemm8(const float* __restrict__ W,
                                      const float (*in)[KD], float acc[8], int tid) {
#pragma unroll 2
  for (int k4 = 0; k4 < KD/4; ++k4) {
    float w0 = W[(k4*4+0)*HID + tid];
    float w1 = W[(k4*4+1)*HID + tid];
    float w2 = W[(k4*4+2)*HID + tid];
    float w3 = W[(k4*4+3)*HID + tid];
#pragma unroll
    for (int r = 0; r < 8; ++r) {
      const float4 v = *reinterpret_cast<const float4*>(&in[r][k4*4]);
      acc[r] = fmaf(v.x, w0, acc[r]);
      acc[r] = fmaf(v.y, w1, acc[r]);
      acc[r] = fmaf(v.z, w2, acc[r]);
      acc[r] = fmaf(v.w, w3, acc[r]);
    }
  }
}

// --------------------------------------------------------- h = relu([emb|z]W)
__global__ __launch_bounds__(128) void k_h(
    const int* __restrict__ atype, const float* __restrict__ z,
    const float* __restrict__ emb, const float* __restrict__ W,
    const float* __restrict__ b, float* __restrict__ h,
    __hip_bfloat16* __restrict__ h_bf) {
  __shared__ __align__(16) float in[8][384];
  int tid = threadIdx.x;
  int row0 = blockIdx.x * 8;
#pragma unroll
  for (int r = 0; r < 8; ++r) {
    int atom = row0 + r;
    in[r][tid]     = emb[atype[atom]*HID + tid];
    int cb = (atom >> 6) * LAT;
    in[r][tid+128] = z[cb + tid];
    in[r][tid+256] = z[cb + 128 + tid];
  }
  __syncthreads();
  float acc[8] = {0,0,0,0,0,0,0,0};
  gemm8<384>(W, in, acc, tid);
  float bias = b[tid];
#pragma unroll
  for (int r = 0; r < 8; ++r) {
    float v = fmaxf(acc[r] + bias, 0.f);
    h[(row0+r)*HID + tid] = v;
    h_bf[(row0+r)*HID + tid] = f2bf(v);
  }
}

// ============ MFMA edge GEMM: out = bf16( [mode1: third +] relu([h_s|h_d|third]@W + b) )
// 64 rows/block, 256 threads (4 waves x 16 rows x 128 cols), K=384
__global__ __launch_bounds__(256) void k_egemm(
    const int* __restrict__ src, const int* __restrict__ dst,
    const __hip_bfloat16* __restrict__ h_bf,
    const __hip_bfloat16* __restrict__ third,   // rbf (mode0) or m (mode1), [e][128] bf16
    const __hip_bfloat16* __restrict__ WT,      // [128][384] bf16, n-major
    const float* __restrict__ b,
    __hip_bfloat16* __restrict__ out, int mode) {
  __shared__ short Abuf[64 * 392];   // 64 rows x 384 bf16, pitch 392 (2-way bank only)
  __shared__ int sidx[64], didx[64];
  const int tid = threadIdx.x;
  const int row0 = blockIdx.x * 64;

  if (tid < 64)        sidx[tid]    = src[row0 + tid];
  else if (tid < 128)  didx[tid-64] = dst[row0 + tid - 64];
  __syncthreads();

  // stage A: 64 rows x 48 16B-chunks = 3072 chunks, 12 per thread
#pragma unroll
  for (int i = 0; i < 12; ++i) {
    int g = i * 256 + tid;
    int r = g / 48, c = g % 48;
    uint4 v;
    if (c < 16)       v = ((const uint4*)(h_bf + (size_t)sidx[r]*HID))[c];
    else if (c < 32)  v = ((const uint4*)(h_bf + (size_t)didx[r]*HID))[c-16];
    else              v = ((const uint4*)(third + (size_t)(row0+r)*HID))[c-32];
    *(uint4*)(&Abuf[r*392 + c*8]) = v;
  }
  __syncthreads();

  const int w = tid >> 6, lane = tid & 63, ln = lane & 15, qd = lane >> 4;
  f32x4 acc[8];
#pragma unroll
  for (int ct = 0; ct < 8; ++ct) acc[ct] = (f32x4){0.f,0.f,0.f,0.f};

  const short* arow = &Abuf[(w*16 + ln)*392 + qd*8];
  const short* Wb   = (const short*)WT + ln*384 + qd*8;
#pragma unroll
  for (int ks = 0; ks < 12; ++ks) {
    short8 a = *(const short8*)(arow + ks*32);
#pragma unroll
    for (int ct = 0; ct < 8; ++ct) {
      short8 bb = *(const short8*)(Wb + ct*16*384 + ks*32);
      acc[ct] = __builtin_amdgcn_mfma_f32_16x16x32_bf16(a, bb, acc[ct], 0, 0, 0);
    }
  }

#pragma unroll
  for (int ct = 0; ct < 8; ++ct) {
    float bias = b[ct*16 + ln];
#pragma unroll
    for (int reg = 0; reg < 4; ++reg) {
      int rl = w*16 + qd*4 + reg;
      float v = fmaxf(acc[ct][reg] + bias, 0.f);
      if (mode) v += (float)bf2f(*(const __hip_bfloat16*)&Abuf[rl*392 + 256 + ct*16 + ln]);
      out[(size_t)(row0 + rl)*HID + ct*16 + ln] = f2bf(v);
    }
  }
}

// ===== fused msg+segsum per crystal: agg = segsum( relu(m@Wm+bm) * (rbf@Wg) )
// 1 block per crystal, 256 threads; 20 chunks of 64 edges; K=128 both GEMMs
__global__ __launch_bounds__(256) void k_msgagg(
    const __hip_bfloat16* __restrict__ m, const __hip_bfloat16* __restrict__ rbf,
    const __hip_bfloat16* __restrict__ WmT, const float* __restrict__ bm,
    const __hip_bfloat16* __restrict__ WgT, const int* __restrict__ dst,
    float* __restrict__ aggG) {
  __shared__ float agg[64 * 132];     // pitch 132: bank = (4d+col)%32
  __shared__ short Am[64 * 136];      // pitch 136 bf16 (272B): 2-way bank only
  __shared__ short Ar[64 * 136];
  __shared__ int   sdst[64];
  __shared__ float sbm[128];
  const int tid = threadIdx.x;
  const int c = blockIdx.x;
  const int w = tid >> 6, lane = tid & 63, ln = lane & 15, qd = lane >> 4;

  for (int i = tid; i < 64*132; i += 256) agg[i] = 0.f;
  if (tid < 128) sbm[tid] = bm[tid];
  __syncthreads();

  for (int ch = 0; ch < 20; ++ch) {
    int e0 = c * 1280 + ch * 64;
    if (tid < 64) sdst[tid] = dst[e0 + tid] & 63;
#pragma unroll
    for (int i = 0; i < 4; ++i) {           // 1024 16B-chunks per array
      int g = i * 256 + tid;
      int r = g >> 4, cc = g & 15;
      *(uint4*)(&Am[r*136 + cc*8]) = ((const uint4*)(m   + (size_t)(e0+r)*HID))[cc];
      *(uint4*)(&Ar[r*136 + cc*8]) = ((const uint4*)(rbf + (size_t)(e0+r)*HID))[cc];
    }
    __syncthreads();

    const short* amr = &Am[(w*16 + ln)*136 + qd*8];
    const short* arr = &Ar[(w*16 + ln)*136 + qd*8];
    short8 am[4], ar[4];
#pragma unroll
    for (int ks = 0; ks < 4; ++ks) { am[ks] = *(const short8*)(amr + ks*32);
                                     ar[ks] = *(const short8*)(arr + ks*32); }
    f32x4 accM[8], accG[8];
#pragma unroll
    for (int ct = 0; ct < 8; ++ct) { accM[ct] = (f32x4){0,0,0,0}; accG[ct] = (f32x4){0,0,0,0}; }
#pragma unroll
    for (int ct = 0; ct < 8; ++ct) {
      const short* bmp = (const short*)WmT + (ct*16 + ln)*128 + qd*8;
      const short* bgp = (const short*)WgT + (ct*16 + ln)*128 + qd*8;
#pragma unroll
      for (int ks = 0; ks < 4; ++ks)
        accM[ct] = __builtin_amdgcn_mfma_f32_16x16x32_bf16(am[ks], *(const short8*)(bmp + ks*32), accM[ct], 0,0,0);
#pragma unroll
      for (int ks = 0; ks < 4; ++ks)
        accG[ct] = __builtin_amdgcn_mfma_f32_16x16x32_bf16(ar[ks], *(const short8*)(bgp + ks*32), accG[ct], 0,0,0);
    }
#pragma unroll
    for (int ct = 0; ct < 8; ++ct) {
      float bias = sbm[ct*16 + ln];
#pragma unroll
      for (int reg = 0; reg < 4; ++reg) {
        int rl = w*16 + qd*4 + reg;
        float v = fmaxf(accM[ct][reg] + bias, 0.f) * accG[ct][reg];
        atomicAdd(&agg[sdst[rl]*132 + ct*16 + ln], v);
      }
    }
    __syncthreads();
  }
  for (int i = tid; i < 64*128; i += 256) {
    int a = i >> 7, col = i & 127;
    aggG[(size_t)(c*64 + a)*HID + col] = agg[a*132 + col];
  }
}

// -------------------------- dense-row K=128 GEMM: Y = relu(X@W+b) [+= mode 1]
__global__ __launch_bounds__(128) void k_fc(
    const float* __restrict__ X, const float* __restrict__ W,
    const float* __restrict__ b, float* __restrict__ Y,
    __hip_bfloat16* __restrict__ Ybf, int mode) {
  __shared__ __align__(16) float ix[8][128];
  int tid = threadIdx.x;
  int row0 = blockIdx.x * 8;
#pragma unroll
  for (int r = 0; r < 8; ++r) ix[r][tid] = X[(row0+r)*HID + tid];
  __syncthreads();
  float acc[8] = {0,0,0,0,0,0,0,0};
  gemm8<128>(W, ix, acc, tid);
  float bias = b[tid];
#pragma unroll
  for (int r = 0; r < 8; ++r) {
    float v = fmaxf(acc[r] + bias, 0.f);
    int o = (row0+r)*HID + tid;
    if (mode) {
      v += Y[o];
      Ybf[o] = f2bf(v);
    }
    Y[o] = v;
  }
}

// ------------------------------------------------- f = m @ W_force + b_force
__global__ void k_force(const __hip_bfloat16* __restrict__ m,
                        const float* __restrict__ Wf,
                        const float* __restrict__ bf, float* __restrict__ f) {
  int lane = threadIdx.x & 63;
  int wave = threadIdx.x >> 6;
  int ebase = blockIdx.x * 64 + wave * 16;
  float w0 = Wf[lane], w1 = Wf[64 + lane];
  float b = bf[0];
  for (int t = 0; t < 16; ++t) {
    int e = ebase + t;
    float p = bf2f(m[(size_t)e*HID + lane]) * w0 + bf2f(m[(size_t)e*HID + 64 + lane]) * w1;
#pragma unroll
    for (int off = 32; off > 0; off >>= 1) p += __shfl_down(p, off, 64);
    if (lane == 0) f[e] = p + b;
  }
}

// ----------------------------------- pred_cart = segsum(f*unit) per crystal
__global__ void k_pcart(const float* __restrict__ f, const float* __restrict__ unit,
                        const int* __restrict__ dst, float* __restrict__ out) {
  __shared__ float acc[AATOMS * 3];
  int c = blockIdx.x, tid = threadIdx.x;  // 256 threads
  if (tid < AATOMS*3) acc[tid] = 0.f;
  __syncthreads();
  for (int t = tid; t < 1280; t += 256) {
    int e = c*1280 + t;
    int d = dst[e] & 63;
    float fv = f[e];
    atomicAdd(&acc[d*3+0], fv * unit[e*3+0]);
    atomicAdd(&acc[d*3+1], fv * unit[e*3+1]);
    atomicAdd(&acc[d*3+2], fv * unit[e*3+2]);
  }
  __syncthreads();
  if (tid < AATOMS*3) out[c*AATOMS*3 + tid] = acc[tid];
}

// ----------------------------------------- final fc3: (128 -> 2) per atom row
__global__ void k_fc3(const float* __restrict__ a2, const float* __restrict__ W,
                      const float* __restrict__ b, float* __restrict__ out) {
  int lane = threadIdx.x & 63;
  int wave = threadIdx.x >> 6;
  int row = blockIdx.x * 4 + wave;
  float x0 = a2[row*HID + lane], x1 = a2[row*HID + 64 + lane];
  float p0 = x0 * W[lane*2+0] + x1 * W[(64+lane)*2+0];
  float p1 = x0 * W[lane*2+1] + x1 * W[(64+lane)*2+1];
#pragma unroll
  for (int off = 32; off > 0; off >>= 1) {
    p0 += __shfl_down(p0, off, 64);
    p1 += __shfl_down(p1, off, 64);
  }
  if (lane == 0) {
    out[row*2+0] = p0 + b[0];
    out[row*2+1] = p1 + b[1];
  }
}

extern "C" void kernel_launch(void* const* d_in, const int* in_sizes, int n_in,
                              void* d_out, int out_size, void* d_ws, size_t ws_size,
                              hipStream_t stream) {
  const float* z        = (const float*)d_in[0];
  const float* frac     = (const float*)d_in[1];
  const float* lengths  = (const float*)d_in[2];
  const float* angles   = (const float*)d_in[3];
  const int*   atype    = (const int*)  d_in[4];
  const int*   src      = (const int*)  d_in[5];
  const int*   dst      = (const int*)  d_in[6];
  const float* emb      = (const float*)d_in[7];
  const float* W_in     = (const float*)d_in[8];
  const float* b_in     = (const float*)d_in[9];
  const float* W_edge   = (const float*)d_in[10];
  const float* b_edge   = (const float*)d_in[11];
  const float* Wb_rbf   = (const float*)d_in[12];
  const float* Wb_msg   = (const float*)d_in[13];
  const float* bb_msg   = (const float*)d_in[14];
  const float* Wb_atom  = (const float*)d_in[15];
  const float* bb_atom  = (const float*)d_in[16];
  const float* Wb_upd   = (const float*)d_in[17];
  const float* bb_upd   = (const float*)d_in[18];
  const float* W_force  = (const float*)d_in[19];
  const float* b_force  = (const float*)d_in[20];
  const float* W_fc1    = (const float*)d_in[21];
  const float* b_fc1    = (const float*)d_in[22];
  const float* W_fc2    = (const float*)d_in[23];
  const float* b_fc2    = (const float*)d_in[24];
  const float* W_fc3    = (const float*)d_in[25];
  const float* b_fc3    = (const float*)d_in[26];

  // ---- workspace layout (~194 MB) ----
  char* p = (char*)d_ws;
  float* cart = (float*)p;            p += (size_t)NATOMS*3*4;
  float* unit = (float*)p;            p += (size_t)NEDGE*3*4;
  float* h    = (float*)p;            p += (size_t)NATOMS*HID*4;
  float* agg  = (float*)p;            p += (size_t)NATOMS*HID*4;
  __hip_bfloat16* h_bf = (__hip_bfloat16*)p; p += (size_t)NATOMS*HID*2;
  __hip_bfloat16* m    = (__hip_bfloat16*)p; p += (size_t)NEDGE*HID*2;   // 84 MB
  __hip_bfloat16* rbf  = (__hip_bfloat16*)p; p += (size_t)NEDGE*NRBF*2;  // 84 MB
  __hip_bfloat16* WT   = (__hip_bfloat16*)p; p += (size_t)294912*2;
  // rbf region dead after last k_msgagg -> overlay epilogue scratch
  float* f  = (float*)rbf;
  float* a1 = f + NEDGE;
  float* a2 = a1 + NATOMS*HID;

  __hip_bfloat16* WT_edge = WT;                    // 128x384
  __hip_bfloat16* WT_upd0 = WT + 49152;            // 3 x 128x384
  __hip_bfloat16* WT_msg0 = WT + 196608;           // 3 x 128x128
  __hip_bfloat16* WT_rbf0 = WT + 245760;           // 3 x 128x128

  float* out_cart = (float*)d_out;
  float* out_at   = out_cart + NATOMS*3;

  k_wcast<<<1152, 256, 0, stream>>>(W_edge, Wb_upd, Wb_msg, Wb_rbf, WT);
  k_cart<<<NATOMS/256, 256, 0, stream>>>(frac, lengths, angles, cart);
  k_edge<<<NEDGE/2, 256, 0, stream>>>(cart, src, dst, unit, rbf);
  k_h<<<NATOMS/8, 128, 0, stream>>>(atype, z, emb, W_in, b_in, h, h_bf);
  k_egemm<<<NEDGE/64, 256, 0, stream>>>(src, dst, h_bf, rbf, WT_edge, b_edge, m, 0);

  for (int i = 0; i < NBLK; ++i) {
    k_msgagg<<<NCRYST, 256, 0, stream>>>(m, rbf, WT_msg0 + i*16384, bb_msg + i*HID,
                                         WT_rbf0 + i*16384, dst, agg);
    k_fc<<<NATOMS/8, 128, 0, stream>>>(agg, Wb_atom + i*HID*HID, bb_atom + i*HID,
                                       h, h_bf, 1);
    k_egemm<<<NEDGE/64, 256, 0, stream>>>(src, dst, h_bf, m, WT_upd0 + i*49152,
                                          bb_upd + i*HID, m, 1);
  }

  k_force<<<NEDGE/64, 256, 0, stream>>>(m, W_force, b_force, f);
  k_pcart<<<NCRYST, 256, 0, stream>>>(f, unit, dst, out_cart);
  k_fc<<<NATOMS/8, 128, 0, stream>>>(h, W_fc1, b_fc1, a1, nullptr, 0);
  k_fc<<<NATOMS/8, 128, 0, stream>>>(a1, W_fc2, b_fc2, a2, nullptr, 0);
  k_fc3<<<NATOMS/4, 256, 0, stream>>>(a2, W_fc3, b_fc3, out_at);
}

// Round 4
// 1826.070 us; speedup vs baseline: 2.3191x; 1.2552x over previous
//
#include <hip/hip_runtime.h>
#include <hip/hip_bf16.h>

#define NCRYST 256
#define AATOMS 64
#define KNBR   20
#define HID    128
#define LAT    256
#define NRBF   128
#define NBLK   3
#define NATOMS (NCRYST * AATOMS)   // 16384
#define NEDGE  (NATOMS * KNBR)     // 327680
#define PI_F   3.14159265358979323846f
#define CUT_F  6.0f

typedef short short8 __attribute__((ext_vector_type(8)));   // 8 bf16 (4 VGPRs)
typedef float f32x4  __attribute__((ext_vector_type(4)));   // MFMA C/D

__device__ __forceinline__ float bf2f(__hip_bfloat16 x) { return __bfloat162float(x); }
__device__ __forceinline__ __hip_bfloat16 f2bf(float x) { return __float2bfloat16(x); }

// ---------------------------------------------------------------- cart coords
__global__ void k_cart(const float* __restrict__ frac, const float* __restrict__ lengths,
                       const float* __restrict__ angles, float* __restrict__ cart) {
  int atom = blockIdx.x * blockDim.x + threadIdx.x;
  if (atom >= NATOMS) return;
  int c = atom >> 6;
  float al = angles[c*3+0] * (PI_F/180.f);
  float be = angles[c*3+1] * (PI_F/180.f);
  float ga = angles[c*3+2] * (PI_F/180.f);
  float ca = cosf(al), cb = cosf(be), cg = cosf(ga), sg = sinf(ga);
  float a = lengths[c*3+0], b = lengths[c*3+1], cl = lengths[c*3+2];
  float cx = cl * cb;
  float cy = cl * (ca - cb*cg) / sg;
  float cz = sqrtf(fmaxf(cl*cl - cx*cx - cy*cy, 1e-8f));
  float f0 = frac[atom*3+0], f1 = frac[atom*3+1], f2 = frac[atom*3+2];
  cart[atom*3+0] = f0*a + f1*(b*cg) + f2*cx;
  cart[atom*3+1] = f1*(b*sg) + f2*cy;
  cart[atom*3+2] = f2*cz;
}

// ---------------- edge geometry: unit vec + rbf (bf16, computed ONCE)
__global__ void k_edge(const float* __restrict__ cart, const int* __restrict__ src,
                       const int* __restrict__ dst, float* __restrict__ unit,
                       __hip_bfloat16* __restrict__ rbf) {
  int e = blockIdx.x * 2 + (threadIdx.x >> 7);
  int j = threadIdx.x & 127;
  int s = src[e], d = dst[e];
  float dx = cart[d*3+0] - cart[s*3+0];
  float dy = cart[d*3+1] - cart[s*3+1];
  float dz = cart[d*3+2] - cart[s*3+2];
  float dd = sqrtf(dx*dx + dy*dy + dz*dz + 1e-12f);
  float inv = 1.f / dd;
  if (j == 0) {
    unit[e*3+0] = dx*inv; unit[e*3+1] = dy*inv; unit[e*3+2] = dz*inv;
  }
  float env = 0.5f * (cosf(PI_F * fminf(dd * (1.f/CUT_F), 1.f)) + 1.f);
  float t = (dd - (float)j * (CUT_F/(NRBF-1))) * ((NRBF-1)/CUT_F);
  rbf[e*NRBF + j] = f2bf(expf(-t*t) * env);
}

// ----------------- weights: transpose + cast to bf16, W_T[n][k] = W[k][n]
__global__ void k_wcast(const float* __restrict__ W_edge, const float* __restrict__ Wb_upd,
                        const float* __restrict__ Wb_msg, const float* __restrict__ Wb_rbf,
                        __hip_bfloat16* __restrict__ WT) {
  int idx = blockIdx.x * 256 + threadIdx.x;
  if (idx < 196608) {
    int j = idx / 49152, t = idx % 49152;
    int n = t / 384, k = t % 384;
    const float* srcW = (j == 0) ? W_edge : (Wb_upd + (j-1)*49152);
    WT[idx] = f2bf(srcW[k*128 + n]);
  } else {
    int t = idx - 196608;
    int j = t / 16384, q = t % 16384;
    int n = q / 128, k = q % 128;
    const float* srcW = (j < 3) ? (Wb_msg + j*16384) : (Wb_rbf + (j-3)*16384);
    WT[idx] = f2bf(srcW[k*128 + n]);
  }
}

// --------------------------------------------------- 8-row block GEMM helper
template<int KD>
__device__ __forceinline__ void gemm8(const float* __restrict__ W,
                                      const float (*in)[KD], float acc[8], int tid) {
#pragma unroll 2
  for (int k4 = 0; k4 < KD/4; ++k4) {
    float w0 = W[(k4*4+0)*HID + tid];
    float w1 = W[(k4*4+1)*HID + tid];
    float w2 = W[(k4*4+2)*HID + tid];
    float w3 = W[(k4*4+3)*HID + tid];
#pragma unroll
    for (int r = 0; r < 8; ++r) {
      const float4 v = *reinterpret_cast<const float4*>(&in[r][k4*4]);
      acc[r] = fmaf(v.x, w0, acc[r]);
      acc[r] = fmaf(v.y, w1, acc[r]);
      acc[r] = fmaf(v.z, w2, acc[r]);
      acc[r] = fmaf(v.w, w3, acc[r]);
    }
  }
}

// --------------------------------------------------------- h = relu([emb|z]W)
__global__ __launch_bounds__(128) void k_h(
    const int* __restrict__ atype, const float* __restrict__ z,
    const float* __restrict__ emb, const float* __restrict__ W,
    const float* __restrict__ b, float* __restrict__ h,
    __hip_bfloat16* __restrict__ h_bf) {
  __shared__ __align__(16) float in[8][384];
  int tid = threadIdx.x;
  int row0 = blockIdx.x * 8;
#pragma unroll
  for (int r = 0; r < 8; ++r) {
    int atom = row0 + r;
    in[r][tid]     = emb[atype[atom]*HID + tid];
    int cb = (atom >> 6) * LAT;
    in[r][tid+128] = z[cb + tid];
    in[r][tid+256] = z[cb + 128 + tid];
  }
  __syncthreads();
  float acc[8] = {0,0,0,0,0,0,0,0};
  gemm8<384>(W, in, acc, tid);
  float bias = b[tid];
#pragma unroll
  for (int r = 0; r < 8; ++r) {
    float v = fmaxf(acc[r] + bias, 0.f);
    h[(row0+r)*HID + tid] = v;
    h_bf[(row0+r)*HID + tid] = f2bf(v);
  }
}

// ============ MFMA edge GEMM, LDS-free / barrier-free.
// out = bf16( [mode1: third +] relu([h_s|h_d|third]@W + b) )
// 256 thr = 4 waves x 32 rows (2 m-tiles); A-frags loaded DIRECT from global.
__global__ __launch_bounds__(256) void k_egemm(
    const int* __restrict__ src, const int* __restrict__ dst,
    const __hip_bfloat16* __restrict__ h_bf,
    const __hip_bfloat16* __restrict__ third,   // rbf (mode0) or m (mode1)
    const __hip_bfloat16* __restrict__ WT,      // [128][384] bf16, n-major
    const float* __restrict__ b,
    __hip_bfloat16* __restrict__ out, int mode) {
  const int tid = threadIdx.x;
  const int w = tid >> 6, lane = tid & 63, ln = lane & 15, qd = lane >> 4;
  const int row0 = blockIdx.x * 128 + w * 32;   // this wave's 32 rows

  const int r_a = row0 + ln;         // m-tile 0 row for this lane
  const int r_b = row0 + 16 + ln;    // m-tile 1 row
  const short* hsA = (const short*)h_bf + (size_t)src[r_a]*HID;
  const short* hdA = (const short*)h_bf + (size_t)dst[r_a]*HID;
  const short* thA = (const short*)third + (size_t)r_a*HID;
  const short* hsB = (const short*)h_bf + (size_t)src[r_b]*HID;
  const short* hdB = (const short*)h_bf + (size_t)dst[r_b]*HID;
  const short* thB = (const short*)third + (size_t)r_b*HID;

  const short* Wb = (const short*)WT + ln*384 + qd*8;

  f32x4 acc0[8], acc1[8];
#pragma unroll
  for (int ct = 0; ct < 8; ++ct) { acc0[ct] = (f32x4){0,0,0,0}; acc1[ct] = (f32x4){0,0,0,0}; }

#define SEG(qa, qb, ksb)                                                        \
  _Pragma("unroll")                                                             \
  for (int k2 = 0; k2 < 4; ++k2) {                                              \
    short8 aA = *(const short8*)((qa) + k2*32 + qd*8);                          \
    short8 aB = *(const short8*)((qb) + k2*32 + qd*8);                          \
    _Pragma("unroll")                                                           \
    for (int ct = 0; ct < 8; ++ct) {                                            \
      short8 bb = *(const short8*)(Wb + ct*6144 + ((ksb)+k2)*32);               \
      acc0[ct] = __builtin_amdgcn_mfma_f32_16x16x32_bf16(aA, bb, acc0[ct],0,0,0);\
      acc1[ct] = __builtin_amdgcn_mfma_f32_16x16x32_bf16(aB, bb, acc1[ct],0,0,0);\
    }                                                                           \
  }

  SEG(hsA, hsB, 0)
  SEG(hdA, hdB, 4)
  SEG(thA, thB, 8)
#undef SEG

#pragma unroll
  for (int mt = 0; mt < 2; ++mt) {
    const f32x4* acc = mt ? acc1 : acc0;
#pragma unroll
    for (int ct = 0; ct < 8; ++ct) {
      float bias = b[ct*16 + ln];
      int col = ct*16 + ln;
#pragma unroll
      for (int reg = 0; reg < 4; ++reg) {
        int row = row0 + mt*16 + qd*4 + reg;
        float v = fmaxf(acc[ct][reg] + bias, 0.f);
        if (mode) v += bf2f(((const __hip_bfloat16*)third)[(size_t)row*HID + col]);
        out[(size_t)row*HID + col] = f2bf(v);
      }
    }
  }
}

// ===== fused msg+segsum per crystal, barrier-free chunk loop.
// agg = segsum( relu(m@Wm+bm) * (rbf@Wg) ); 1 block/crystal, 512 thr = 8 waves.
// 80 sub-tiles of 16 edges; wave w handles tiles w, w+8, ... (10 each).
__global__ __launch_bounds__(512) void k_msgagg(
    const __hip_bfloat16* __restrict__ m, const __hip_bfloat16* __restrict__ rbf,
    const __hip_bfloat16* __restrict__ WmT, const float* __restrict__ bm,
    const __hip_bfloat16* __restrict__ WgT, const int* __restrict__ dst,
    float* __restrict__ aggG) {
  __shared__ float agg[64 * 132];     // 33 KB; pitch 132 spreads dst rows over banks
  const int tid = threadIdx.x;
  const int c = blockIdx.x;
  const int w = tid >> 6, lane = tid & 63, ln = lane & 15, qd = lane >> 4;

  for (int i = tid; i < 64*132; i += 512) agg[i] = 0.f;
  __syncthreads();

  for (int s = w; s < 80; s += 8) {
    int e0 = c * 1280 + s * 16;
    const short* pm = (const short*)m   + (size_t)(e0 + ln)*HID + qd*8;
    const short* pr = (const short*)rbf + (size_t)(e0 + ln)*HID + qd*8;
    short8 am[4], ar[4];
#pragma unroll
    for (int ks = 0; ks < 4; ++ks) {
      am[ks] = *(const short8*)(pm + ks*32);
      ar[ks] = *(const short8*)(pr + ks*32);
    }
    int d4[4];
#pragma unroll
    for (int reg = 0; reg < 4; ++reg) d4[reg] = dst[e0 + qd*4 + reg] & 63;

    f32x4 accM[8], accG[8];
#pragma unroll
    for (int ct = 0; ct < 8; ++ct) { accM[ct] = (f32x4){0,0,0,0}; accG[ct] = (f32x4){0,0,0,0}; }
#pragma unroll
    for (int ct = 0; ct < 8; ++ct) {
      const short* bmp = (const short*)WmT + (ct*16 + ln)*128 + qd*8;
      const short* bgp = (const short*)WgT + (ct*16 + ln)*128 + qd*8;
#pragma unroll
      for (int ks = 0; ks < 4; ++ks) {
        accM[ct] = __builtin_amdgcn_mfma_f32_16x16x32_bf16(am[ks], *(const short8*)(bmp + ks*32), accM[ct], 0,0,0);
        accG[ct] = __builtin_amdgcn_mfma_f32_16x16x32_bf16(ar[ks], *(const short8*)(bgp + ks*32), accG[ct], 0,0,0);
      }
    }
#pragma unroll
    for (int ct = 0; ct < 8; ++ct) {
      float bias = bm[ct*16 + ln];
#pragma unroll
      for (int reg = 0; reg < 4; ++reg) {
        float v = fmaxf(accM[ct][reg] + bias, 0.f) * accG[ct][reg];
        atomicAdd(&agg[d4[reg]*132 + ct*16 + ln], v);
      }
    }
  }
  __syncthreads();
  for (int i = tid; i < 64*128; i += 512) {
    int a = i >> 7, col = i & 127;
    aggG[(size_t)(c*64 + a)*HID + col] = agg[a*132 + col];
  }
}

// -------------------------- dense-row K=128 GEMM: Y = relu(X@W+b) [+= mode 1]
__global__ __launch_bounds__(128) void k_fc(
    const float* __restrict__ X, const float* __restrict__ W,
    const float* __restrict__ b, float* __restrict__ Y,
    __hip_bfloat16* __restrict__ Ybf, int mode) {
  __shared__ __align__(16) float ix[8][128];
  int tid = threadIdx.x;
  int row0 = blockIdx.x * 8;
#pragma unroll
  for (int r = 0; r < 8; ++r) ix[r][tid] = X[(row0+r)*HID + tid];
  __syncthreads();
  float acc[8] = {0,0,0,0,0,0,0,0};
  gemm8<128>(W, ix, acc, tid);
  float bias = b[tid];
#pragma unroll
  for (int r = 0; r < 8; ++r) {
    float v = fmaxf(acc[r] + bias, 0.f);
    int o = (row0+r)*HID + tid;
    if (mode) {
      v += Y[o];
      Ybf[o] = f2bf(v);
    }
    Y[o] = v;
  }
}

// ------------------------------------------------- f = m @ W_force + b_force
__global__ void k_force(const __hip_bfloat16* __restrict__ m,
                        const float* __restrict__ Wf,
                        const float* __restrict__ bf, float* __restrict__ f) {
  int lane = threadIdx.x & 63;
  int wave = threadIdx.x >> 6;
  int ebase = blockIdx.x * 64 + wave * 16;
  float w0 = Wf[lane], w1 = Wf[64 + lane];
  float b = bf[0];
  for (int t = 0; t < 16; ++t) {
    int e = ebase + t;
    float p = bf2f(m[(size_t)e*HID + lane]) * w0 + bf2f(m[(size_t)e*HID + 64 + lane]) * w1;
#pragma unroll
    for (int off = 32; off > 0; off >>= 1) p += __shfl_down(p, off, 64);
    if (lane == 0) f[e] = p + b;
  }
}

// ----------------------------------- pred_cart = segsum(f*unit) per crystal
__global__ void k_pcart(const float* __restrict__ f, const float* __restrict__ unit,
                        const int* __restrict__ dst, float* __restrict__ out) {
  __shared__ float acc[AATOMS * 3];
  int c = blockIdx.x, tid = threadIdx.x;  // 256 threads
  if (tid < AATOMS*3) acc[tid] = 0.f;
  __syncthreads();
  for (int t = tid; t < 1280; t += 256) {
    int e = c*1280 + t;
    int d = dst[e] & 63;
    float fv = f[e];
    atomicAdd(&acc[d*3+0], fv * unit[e*3+0]);
    atomicAdd(&acc[d*3+1], fv * unit[e*3+1]);
    atomicAdd(&acc[d*3+2], fv * unit[e*3+2]);
  }
  __syncthreads();
  if (tid < AATOMS*3) out[c*AATOMS*3 + tid] = acc[tid];
}

// ----------------------------------------- final fc3: (128 -> 2) per atom row
__global__ void k_fc3(const float* __restrict__ a2, const float* __restrict__ W,
                      const float* __restrict__ b, float* __restrict__ out) {
  int lane = threadIdx.x & 63;
  int wave = threadIdx.x >> 6;
  int row = blockIdx.x * 4 + wave;
  float x0 = a2[row*HID + lane], x1 = a2[row*HID + 64 + lane];
  float p0 = x0 * W[lane*2+0] + x1 * W[(64+lane)*2+0];
  float p1 = x0 * W[lane*2+1] + x1 * W[(64+lane)*2+1];
#pragma unroll
  for (int off = 32; off > 0; off >>= 1) {
    p0 += __shfl_down(p0, off, 64);
    p1 += __shfl_down(p1, off, 64);
  }
  if (lane == 0) {
    out[row*2+0] = p0 + b[0];
    out[row*2+1] = p1 + b[1];
  }
}

extern "C" void kernel_launch(void* const* d_in, const int* in_sizes, int n_in,
                              void* d_out, int out_size, void* d_ws, size_t ws_size,
                              hipStream_t stream) {
  const float* z        = (const float*)d_in[0];
  const float* frac     = (const float*)d_in[1];
  const float* lengths  = (const float*)d_in[2];
  const float* angles   = (const float*)d_in[3];
  const int*   atype    = (const int*)  d_in[4];
  const int*   src      = (const int*)  d_in[5];
  const int*   dst      = (const int*)  d_in[6];
  const float* emb      = (const float*)d_in[7];
  const float* W_in     = (const float*)d_in[8];
  const float* b_in     = (const float*)d_in[9];
  const float* W_edge   = (const float*)d_in[10];
  const float* b_edge   = (const float*)d_in[11];
  const float* Wb_rbf   = (const float*)d_in[12];
  const float* Wb_msg   = (const float*)d_in[13];
  const float* bb_msg   = (const float*)d_in[14];
  const float* Wb_atom  = (const float*)d_in[15];
  const float* bb_atom  = (const float*)d_in[16];
  const float* Wb_upd   = (const float*)d_in[17];
  const float* bb_upd   = (const float*)d_in[18];
  const float* W_force  = (const float*)d_in[19];
  const float* b_force  = (const float*)d_in[20];
  const float* W_fc1    = (const float*)d_in[21];
  const float* b_fc1    = (const float*)d_in[22];
  const float* W_fc2    = (const float*)d_in[23];
  const float* b_fc2    = (const float*)d_in[24];
  const float* W_fc3    = (const float*)d_in[25];
  const float* b_fc3    = (const float*)d_in[26];

  // ---- workspace layout (~194 MB) ----
  char* p = (char*)d_ws;
  float* cart = (float*)p;            p += (size_t)NATOMS*3*4;
  float* unit = (float*)p;            p += (size_t)NEDGE*3*4;
  float* h    = (float*)p;            p += (size_t)NATOMS*HID*4;
  float* agg  = (float*)p;            p += (size_t)NATOMS*HID*4;
  __hip_bfloat16* h_bf = (__hip_bfloat16*)p; p += (size_t)NATOMS*HID*2;
  __hip_bfloat16* m    = (__hip_bfloat16*)p; p += (size_t)NEDGE*HID*2;   // 84 MB
  __hip_bfloat16* rbf  = (__hip_bfloat16*)p; p += (size_t)NEDGE*NRBF*2;  // 84 MB
  __hip_bfloat16* WT   = (__hip_bfloat16*)p; p += (size_t)294912*2;
  // rbf region dead after last k_msgagg -> overlay epilogue scratch
  float* f  = (float*)rbf;
  float* a1 = f + NEDGE;
  float* a2 = a1 + NATOMS*HID;

  __hip_bfloat16* WT_edge = WT;                    // 128x384
  __hip_bfloat16* WT_upd0 = WT + 49152;            // 3 x 128x384
  __hip_bfloat16* WT_msg0 = WT + 196608;           // 3 x 128x128
  __hip_bfloat16* WT_rbf0 = WT + 245760;           // 3 x 128x128

  float* out_cart = (float*)d_out;
  float* out_at   = out_cart + NATOMS*3;

  k_wcast<<<1152, 256, 0, stream>>>(W_edge, Wb_upd, Wb_msg, Wb_rbf, WT);
  k_cart<<<NATOMS/256, 256, 0, stream>>>(frac, lengths, angles, cart);
  k_edge<<<NEDGE/2, 256, 0, stream>>>(cart, src, dst, unit, rbf);
  k_h<<<NATOMS/8, 128, 0, stream>>>(atype, z, emb, W_in, b_in, h, h_bf);
  k_egemm<<<NEDGE/128, 256, 0, stream>>>(src, dst, h_bf, rbf, WT_edge, b_edge, m, 0);

  for (int i = 0; i < NBLK; ++i) {
    k_msgagg<<<NCRYST, 512, 0, stream>>>(m, rbf, WT_msg0 + i*16384, bb_msg + i*HID,
                                         WT_rbf0 + i*16384, dst, agg);
    k_fc<<<NATOMS/8, 128, 0, stream>>>(agg, Wb_atom + i*HID*HID, bb_atom + i*HID,
                                       h, h_bf, 1);
    k_egemm<<<NEDGE/128, 256, 0, stream>>>(src, dst, h_bf, m, WT_upd0 + i*49152,
                                           bb_upd + i*HID, m, 1);
  }

  k_force<<<NEDGE/64, 256, 0, stream>>>(m, W_force, b_force, f);
  k_pcart<<<NCRYST, 256, 0, stream>>>(f, unit, dst, out_cart);
  k_fc<<<NATOMS/8, 128, 0, stream>>>(h, W_fc1, b_fc1, a1, nullptr, 0);
  k_fc<<<NATOMS/8, 128, 0, stream>>>(a1, W_fc2, b_fc2, a2, nullptr, 0);
  k_fc3<<<NATOMS/4, 256, 0, stream>>>(a2, W_fc3, b_fc3, out_at);
}